// Round 1
// baseline (1305.841 us; speedup 1.0000x reference)
//
#include <hip/hip_runtime.h>
#include <math.h>

// Problem dims (fixed)
constexpr int S_ = 512;
constexpr int B_ = 2;
constexpr int H_ = 1024;
constexpr int I_ = 2816;
constexpr int E_ = 8;
constexpr int T_ = S_ * B_;   // 1024 tokens

// ws layout:
//   int counts[8]
//   int tlist[8 * 1024]
//   float act[1024 * 2816]   (act = silu(g)*u, indexed by token id)

__global__ __launch_bounds__(64) void init_counts_kernel(int* __restrict__ counts) {
    if (threadIdx.x < E_) counts[threadIdx.x] = 0;
}

__global__ __launch_bounds__(64) void router_kernel(const float* __restrict__ hidden,
                                                    const float* __restrict__ rw,
                                                    int* __restrict__ counts,
                                                    int* __restrict__ tlist) {
    const int t = blockIdx.x;
    const int lane = threadIdx.x;
    const float* x = hidden + (size_t)t * H_;
    float acc[E_];
#pragma unroll
    for (int e = 0; e < E_; e++) acc[e] = 0.f;
    for (int h = lane; h < H_; h += 64) {
        float xv = x[h];
#pragma unroll
        for (int e = 0; e < E_; e++) acc[e] = fmaf(xv, rw[e * H_ + h], acc[e]);
    }
#pragma unroll
    for (int e = 0; e < E_; e++) {
#pragma unroll
        for (int off = 32; off >= 1; off >>= 1)
            acc[e] += __shfl_xor(acc[e], off, 64);
    }
    if (lane == 0) {
        int best = 0;
        float bv = acc[0];
#pragma unroll
        for (int e = 1; e < E_; e++) {
            if (acc[e] > bv) { bv = acc[e]; best = e; }  // strict > : first max wins
        }
        int pos = atomicAdd(&counts[best], 1);
        tlist[best * T_ + pos] = t;
    }
}

// Phase A: for expert e, token tile tt (64 tokens), I tile (64 rows):
//   G = X @ gate_w[e]^T, U = X @ up_w[e]^T, act = silu(G)*U
__global__ __launch_bounds__(256) void gateup_kernel(const float* __restrict__ hidden,
                                                     const float* __restrict__ gate_w,
                                                     const float* __restrict__ up_w,
                                                     const int* __restrict__ counts,
                                                     const int* __restrict__ tlist,
                                                     float* __restrict__ act) {
    const int e  = blockIdx.y >> 4;
    const int tt = blockIdx.y & 15;
    const int cnt = counts[e];
    if (tt * 64 >= cnt) return;
    const int i0 = blockIdx.x * 64;
    const int tid = threadIdx.x;

    __shared__ float Xs[64][33];
    __shared__ float Gs[64][33];
    __shared__ float Us[64][33];
    __shared__ int toks[64];

    if (tid < 64) {
        int p = tt * 64 + tid;
        toks[tid] = (p < cnt) ? tlist[e * T_ + p] : -1;
    }
    __syncthreads();

    const float* gw = gate_w + (size_t)e * I_ * H_ + (size_t)i0 * H_;
    const float* uw = up_w   + (size_t)e * I_ * H_ + (size_t)i0 * H_;

    float accg[4][4];
    float accu[4][4];
#pragma unroll
    for (int i = 0; i < 4; i++)
#pragma unroll
        for (int j = 0; j < 4; j++) { accg[i][j] = 0.f; accu[i][j] = 0.f; }

    const int tx = tid & 15;
    const int ty = tid >> 4;

    for (int k0 = 0; k0 < H_; k0 += 32) {
        __syncthreads();
#pragma unroll
        for (int f = 0; f < 2; f++) {
            int idx = tid + f * 256;       // 0..511
            int row = idx >> 3;            // 0..63
            int c4  = (idx & 7) << 2;      // 0,4,...,28
            int tok = toks[row];
            float4 xv = make_float4(0.f, 0.f, 0.f, 0.f);
            if (tok >= 0) xv = *(const float4*)(hidden + (size_t)tok * H_ + k0 + c4);
            Xs[row][c4 + 0] = xv.x; Xs[row][c4 + 1] = xv.y;
            Xs[row][c4 + 2] = xv.z; Xs[row][c4 + 3] = xv.w;
            float4 gv = *(const float4*)(gw + (size_t)row * H_ + k0 + c4);
            Gs[row][c4 + 0] = gv.x; Gs[row][c4 + 1] = gv.y;
            Gs[row][c4 + 2] = gv.z; Gs[row][c4 + 3] = gv.w;
            float4 uv = *(const float4*)(uw + (size_t)row * H_ + k0 + c4);
            Us[row][c4 + 0] = uv.x; Us[row][c4 + 1] = uv.y;
            Us[row][c4 + 2] = uv.z; Us[row][c4 + 3] = uv.w;
        }
        __syncthreads();
#pragma unroll 8
        for (int k = 0; k < 32; k++) {
            float a[4], g[4], u[4];
#pragma unroll
            for (int i = 0; i < 4; i++) a[i] = Xs[ty * 4 + i][k];
#pragma unroll
            for (int j = 0; j < 4; j++) { g[j] = Gs[tx * 4 + j][k]; u[j] = Us[tx * 4 + j][k]; }
#pragma unroll
            for (int i = 0; i < 4; i++)
#pragma unroll
                for (int j = 0; j < 4; j++) {
                    accg[i][j] = fmaf(a[i], g[j], accg[i][j]);
                    accu[i][j] = fmaf(a[i], u[j], accu[i][j]);
                }
        }
    }

#pragma unroll
    for (int i = 0; i < 4; i++) {
        int tok = toks[ty * 4 + i];
        if (tok < 0) continue;
#pragma unroll
        for (int j = 0; j < 4; j++) {
            float g = accg[i][j];
            float u = accu[i][j];
            float s = g / (1.f + expf(-g));   // silu
            act[(size_t)tok * I_ + i0 + tx * 4 + j] = s * u;
        }
    }
}

// Phase B: Y = act @ down_w[e]^T  (down_w[e] is [H, I], K = I)
__global__ __launch_bounds__(256) void down_kernel(const float* __restrict__ act,
                                                   const float* __restrict__ down_w,
                                                   const int* __restrict__ counts,
                                                   const int* __restrict__ tlist,
                                                   float* __restrict__ out) {
    const int e  = blockIdx.y >> 4;
    const int tt = blockIdx.y & 15;
    const int cnt = counts[e];
    if (tt * 64 >= cnt) return;
    const int h0 = blockIdx.x * 64;
    const int tid = threadIdx.x;

    __shared__ float As[64][33];
    __shared__ float Ds[64][33];
    __shared__ int toks[64];

    if (tid < 64) {
        int p = tt * 64 + tid;
        toks[tid] = (p < cnt) ? tlist[e * T_ + p] : -1;
    }
    __syncthreads();

    const float* dw = down_w + (size_t)e * H_ * I_ + (size_t)h0 * I_;

    float acc[4][4];
#pragma unroll
    for (int i = 0; i < 4; i++)
#pragma unroll
        for (int j = 0; j < 4; j++) acc[i][j] = 0.f;

    const int tx = tid & 15;
    const int ty = tid >> 4;

    for (int k0 = 0; k0 < I_; k0 += 32) {
        __syncthreads();
#pragma unroll
        for (int f = 0; f < 2; f++) {
            int idx = tid + f * 256;
            int row = idx >> 3;
            int c4  = (idx & 7) << 2;
            int tok = toks[row];
            float4 av = make_float4(0.f, 0.f, 0.f, 0.f);
            if (tok >= 0) av = *(const float4*)(act + (size_t)tok * I_ + k0 + c4);
            As[row][c4 + 0] = av.x; As[row][c4 + 1] = av.y;
            As[row][c4 + 2] = av.z; As[row][c4 + 3] = av.w;
            float4 dv = *(const float4*)(dw + (size_t)row * I_ + k0 + c4);
            Ds[row][c4 + 0] = dv.x; Ds[row][c4 + 1] = dv.y;
            Ds[row][c4 + 2] = dv.z; Ds[row][c4 + 3] = dv.w;
        }
        __syncthreads();
#pragma unroll 8
        for (int k = 0; k < 32; k++) {
            float a[4], d[4];
#pragma unroll
            for (int i = 0; i < 4; i++) a[i] = As[ty * 4 + i][k];
#pragma unroll
            for (int j = 0; j < 4; j++) d[j] = Ds[tx * 4 + j][k];
#pragma unroll
            for (int i = 0; i < 4; i++)
#pragma unroll
                for (int j = 0; j < 4; j++)
                    acc[i][j] = fmaf(a[i], d[j], acc[i][j]);
        }
    }

#pragma unroll
    for (int i = 0; i < 4; i++) {
        int tok = toks[ty * 4 + i];
        if (tok < 0) continue;
#pragma unroll
        for (int j = 0; j < 4; j++)
            out[(size_t)tok * H_ + h0 + tx * 4 + j] = acc[i][j];
    }
}

extern "C" void kernel_launch(void* const* d_in, const int* in_sizes, int n_in,
                              void* d_out, int out_size, void* d_ws, size_t ws_size,
                              hipStream_t stream) {
    const float* hidden = (const float*)d_in[0];
    const float* rw     = (const float*)d_in[1];
    const float* gate_w = (const float*)d_in[2];
    const float* up_w   = (const float*)d_in[3];
    const float* down_w = (const float*)d_in[4];
    float* out = (float*)d_out;

    int* counts = (int*)d_ws;
    int* tlist  = counts + E_;
    float* act  = (float*)(tlist + E_ * T_);   // byte offset 32800, 16B-aligned

    hipLaunchKernelGGL(init_counts_kernel, dim3(1), dim3(64), 0, stream, counts);
    hipLaunchKernelGGL(router_kernel, dim3(T_), dim3(64), 0, stream, hidden, rw, counts, tlist);
    // grid.y = E * 16 token tiles (16 = T/64 worst case); empty tiles early-exit
    hipLaunchKernelGGL(gateup_kernel, dim3(I_ / 64, E_ * 16), dim3(256), 0, stream,
                       hidden, gate_w, up_w, counts, tlist, act);
    hipLaunchKernelGGL(down_kernel, dim3(H_ / 64, E_ * 16), dim3(256), 0, stream,
                       act, down_w, counts, tlist, out);
}

// Round 2
// 441.179 us; speedup vs baseline: 2.9599x; 2.9599x over previous
//
#include <hip/hip_runtime.h>
#include <math.h>

// Problem dims (fixed)
constexpr int H_ = 1024;
constexpr int I_ = 2816;
constexpr int E_ = 8;
constexpr int T_ = 1024;   // S*B tokens

typedef __bf16 bf16x8 __attribute__((ext_vector_type(8)));
typedef float f32x4 __attribute__((ext_vector_type(4)));

__device__ __forceinline__ ushort f2bf(float f) {
    uint32_t u = __float_as_uint(f);
    u += 0x7fff + ((u >> 16) & 1);   // round-to-nearest-even
    return (ushort)(u >> 16);
}
__device__ __forceinline__ uint pack2(float lo, float hi) {
    return (uint)f2bf(lo) | ((uint)f2bf(hi) << 16);
}

// ws layout: int counts[8]; int tlist[8*1024]; ushort act[1024*2816]

__global__ __launch_bounds__(64) void init_counts_kernel(int* __restrict__ counts) {
    if (threadIdx.x < E_) counts[threadIdx.x] = 0;
}

__global__ __launch_bounds__(64) void router_kernel(const float* __restrict__ hidden,
                                                    const float* __restrict__ rw,
                                                    int* __restrict__ counts,
                                                    int* __restrict__ tlist) {
    const int t = blockIdx.x;
    const int lane = threadIdx.x;
    const float* x = hidden + (size_t)t * H_;
    float acc[E_];
#pragma unroll
    for (int e = 0; e < E_; e++) acc[e] = 0.f;
    for (int h = lane; h < H_; h += 64) {
        float xv = x[h];
#pragma unroll
        for (int e = 0; e < E_; e++) acc[e] = fmaf(xv, rw[e * H_ + h], acc[e]);
    }
#pragma unroll
    for (int e = 0; e < E_; e++) {
#pragma unroll
        for (int off = 32; off >= 1; off >>= 1)
            acc[e] += __shfl_xor(acc[e], off, 64);
    }
    if (lane == 0) {
        int best = 0;
        float bv = acc[0];
#pragma unroll
        for (int e = 1; e < E_; e++) {
            if (acc[e] > bv) { bv = acc[e]; best = e; }  // strict > : first max wins
        }
        int pos = atomicAdd(&counts[best], 1);
        tlist[best * T_ + pos] = t;
    }
}

// Phase A: tile = 128 tokens (M) x 64 I-rows (N), K=H=1024, BK=64, bf16 MFMA.
// act[tok][i] = silu(g)*u stored as bf16.
__global__ __launch_bounds__(256) void gateup_kernel(const float* __restrict__ hidden,
                                                     const float* __restrict__ gate_w,
                                                     const float* __restrict__ up_w,
                                                     const int* __restrict__ counts,
                                                     const int* __restrict__ tlist,
                                                     ushort* __restrict__ act) {
    const int e  = blockIdx.y >> 3;
    const int tt = blockIdx.y & 7;
    const int cnt = counts[e];
    if (tt * 128 >= cnt) return;
    const int i0 = blockIdx.x * 64;
    const int tid = threadIdx.x;

    __shared__ ushort Xs[128 * 72];   // tokens x k, bf16, stride 72 (144B: 2-way free)
    __shared__ ushort Gs[64 * 72];
    __shared__ ushort Us[64 * 72];
    __shared__ int toks[128];

    if (tid < 128) {
        int p = tt * 128 + tid;
        toks[tid] = (p < cnt) ? tlist[e * T_ + p] : -1;
    }
    __syncthreads();

    const float* gw = gate_w + (size_t)e * I_ * H_ + (size_t)i0 * H_;
    const float* uw = up_w   + (size_t)e * I_ * H_ + (size_t)i0 * H_;

    f32x4 accg[8], accu[8];
#pragma unroll
    for (int mi = 0; mi < 8; mi++) {
        accg[mi] = (f32x4){0.f, 0.f, 0.f, 0.f};
        accu[mi] = (f32x4){0.f, 0.f, 0.f, 0.f};
    }

    const int wv = tid >> 6;
    const int lane = tid & 63;
    const int quad = lane >> 4;
    const int l15 = lane & 15;

    for (int k0 = 0; k0 < H_; k0 += 64) {
        // issue global loads before the barrier (overlap with prior compute)
        float4 xv[8];
#pragma unroll
        for (int p = 0; p < 8; p++) {
            int idx = tid + p * 256;
            int row = idx >> 4, c4 = (idx & 15) << 2;
            int tok = toks[row];
            xv[p] = (tok >= 0) ? *(const float4*)(hidden + (size_t)tok * H_ + k0 + c4)
                               : make_float4(0.f, 0.f, 0.f, 0.f);
        }
        float4 gv[4], uv[4];
#pragma unroll
        for (int p = 0; p < 4; p++) {
            int idx = tid + p * 256;
            int row = idx >> 4, c4 = (idx & 15) << 2;
            gv[p] = *(const float4*)(gw + (size_t)row * H_ + k0 + c4);
            uv[p] = *(const float4*)(uw + (size_t)row * H_ + k0 + c4);
        }
        __syncthreads();   // prior iter's LDS reads complete
#pragma unroll
        for (int p = 0; p < 8; p++) {
            int idx = tid + p * 256;
            int row = idx >> 4, c4 = (idx & 15) << 2;
            *(uint2*)&Xs[row * 72 + c4] = (uint2){pack2(xv[p].x, xv[p].y), pack2(xv[p].z, xv[p].w)};
        }
#pragma unroll
        for (int p = 0; p < 4; p++) {
            int idx = tid + p * 256;
            int row = idx >> 4, c4 = (idx & 15) << 2;
            *(uint2*)&Gs[row * 72 + c4] = (uint2){pack2(gv[p].x, gv[p].y), pack2(gv[p].z, gv[p].w)};
            *(uint2*)&Us[row * 72 + c4] = (uint2){pack2(uv[p].x, uv[p].y), pack2(uv[p].z, uv[p].w)};
        }
        __syncthreads();
#pragma unroll
        for (int kk = 0; kk < 64; kk += 32) {
            const int kb = kk + quad * 8;
            bf16x8 bg = *(const bf16x8*)&Gs[(wv * 16 + l15) * 72 + kb];
            bf16x8 bu = *(const bf16x8*)&Us[(wv * 16 + l15) * 72 + kb];
#pragma unroll
            for (int mi = 0; mi < 8; mi++) {
                bf16x8 a = *(const bf16x8*)&Xs[(mi * 16 + l15) * 72 + kb];
                accg[mi] = __builtin_amdgcn_mfma_f32_16x16x32_bf16(a, bg, accg[mi], 0, 0, 0);
                accu[mi] = __builtin_amdgcn_mfma_f32_16x16x32_bf16(a, bu, accu[mi], 0, 0, 0);
            }
        }
        __syncthreads();
    }

    // epilogue: D row = token (quad*4+reg within frag), col = i (lane&15)
#pragma unroll
    for (int mi = 0; mi < 8; mi++) {
#pragma unroll
        for (int r = 0; r < 4; r++) {
            int tok = toks[mi * 16 + quad * 4 + r];
            if (tok < 0) continue;
            float g = accg[mi][r], u = accu[mi][r];
            float s = g / (1.f + __expf(-g)) * u;
            act[(size_t)tok * I_ + i0 + wv * 16 + l15] = f2bf(s);
        }
    }
}

// Phase B: tile = 128 tokens (M) x 32 H-rows (N), K=I=2816, BK=64.
__global__ __launch_bounds__(256) void down_kernel(const ushort* __restrict__ act,
                                                   const float* __restrict__ down_w,
                                                   const int* __restrict__ counts,
                                                   const int* __restrict__ tlist,
                                                   float* __restrict__ out) {
    const int e  = blockIdx.y >> 3;
    const int tt = blockIdx.y & 7;
    const int cnt = counts[e];
    if (tt * 128 >= cnt) return;
    const int h0 = blockIdx.x * 32;
    const int tid = threadIdx.x;

    __shared__ ushort As[128 * 72];
    __shared__ ushort Ds[32 * 72];
    __shared__ int toks[128];

    if (tid < 128) {
        int p = tt * 128 + tid;
        toks[tid] = (p < cnt) ? tlist[e * T_ + p] : -1;
    }
    __syncthreads();

    const float* dw = down_w + (size_t)e * H_ * I_ + (size_t)h0 * I_;

    f32x4 acc[2][2];
#pragma unroll
    for (int mi = 0; mi < 2; mi++)
#pragma unroll
        for (int nj = 0; nj < 2; nj++) acc[mi][nj] = (f32x4){0.f, 0.f, 0.f, 0.f};

    const int wv = tid >> 6;
    const int lane = tid & 63;
    const int quad = lane >> 4;
    const int l15 = lane & 15;

    for (int k0 = 0; k0 < I_; k0 += 64) {
        uint4 av[4];
#pragma unroll
        for (int p = 0; p < 4; p++) {
            int idx = tid + p * 256;
            int row = idx >> 3, c8 = (idx & 7) << 3;
            int tok = toks[row];
            av[p] = (tok >= 0) ? *(const uint4*)(act + (size_t)tok * I_ + k0 + c8)
                               : (uint4){0u, 0u, 0u, 0u};
        }
        float4 dv[2];
#pragma unroll
        for (int p = 0; p < 2; p++) {
            int idx = tid + p * 256;
            int row = idx >> 4, c4 = (idx & 15) << 2;
            dv[p] = *(const float4*)(dw + (size_t)row * I_ + k0 + c4);
        }
        __syncthreads();
#pragma unroll
        for (int p = 0; p < 4; p++) {
            int idx = tid + p * 256;
            int row = idx >> 3, c8 = (idx & 7) << 3;
            *(uint4*)&As[row * 72 + c8] = av[p];
        }
#pragma unroll
        for (int p = 0; p < 2; p++) {
            int idx = tid + p * 256;
            int row = idx >> 4, c4 = (idx & 15) << 2;
            *(uint2*)&Ds[row * 72 + c4] = (uint2){pack2(dv[p].x, dv[p].y), pack2(dv[p].z, dv[p].w)};
        }
        __syncthreads();
#pragma unroll
        for (int kk = 0; kk < 64; kk += 32) {
            const int kb = kk + quad * 8;
            bf16x8 a0 = *(const bf16x8*)&As[(wv * 32 +      l15) * 72 + kb];
            bf16x8 a1 = *(const bf16x8*)&As[(wv * 32 + 16 + l15) * 72 + kb];
            bf16x8 b0 = *(const bf16x8*)&Ds[(     l15) * 72 + kb];
            bf16x8 b1 = *(const bf16x8*)&Ds[(16 + l15) * 72 + kb];
            acc[0][0] = __builtin_amdgcn_mfma_f32_16x16x32_bf16(a0, b0, acc[0][0], 0, 0, 0);
            acc[0][1] = __builtin_amdgcn_mfma_f32_16x16x32_bf16(a0, b1, acc[0][1], 0, 0, 0);
            acc[1][0] = __builtin_amdgcn_mfma_f32_16x16x32_bf16(a1, b0, acc[1][0], 0, 0, 0);
            acc[1][1] = __builtin_amdgcn_mfma_f32_16x16x32_bf16(a1, b1, acc[1][1], 0, 0, 0);
        }
        __syncthreads();
    }

#pragma unroll
    for (int mi = 0; mi < 2; mi++) {
#pragma unroll
        for (int r = 0; r < 4; r++) {
            int tok = toks[wv * 32 + mi * 16 + quad * 4 + r];
            if (tok < 0) continue;
#pragma unroll
            for (int nj = 0; nj < 2; nj++)
                out[(size_t)tok * H_ + h0 + nj * 16 + l15] = acc[mi][nj][r];
        }
    }
}

extern "C" void kernel_launch(void* const* d_in, const int* in_sizes, int n_in,
                              void* d_out, int out_size, void* d_ws, size_t ws_size,
                              hipStream_t stream) {
    const float* hidden = (const float*)d_in[0];
    const float* rw     = (const float*)d_in[1];
    const float* gate_w = (const float*)d_in[2];
    const float* up_w   = (const float*)d_in[3];
    const float* down_w = (const float*)d_in[4];
    float* out = (float*)d_out;

    int* counts = (int*)d_ws;
    int* tlist  = counts + E_;
    ushort* act = (ushort*)(tlist + E_ * T_);   // byte offset 32800, 16B-aligned

    hipLaunchKernelGGL(init_counts_kernel, dim3(1), dim3(64), 0, stream, counts);
    hipLaunchKernelGGL(router_kernel, dim3(T_), dim3(64), 0, stream, hidden, rw, counts, tlist);
    hipLaunchKernelGGL(gateup_kernel, dim3(I_ / 64, E_ * 8), dim3(256), 0, stream,
                       hidden, gate_w, up_w, counts, tlist, act);
    hipLaunchKernelGGL(down_kernel, dim3(H_ / 32, E_ * 8), dim3(256), 0, stream,
                       act, down_w, counts, tlist, out);
}

// Round 3
// 385.306 us; speedup vs baseline: 3.3891x; 1.1450x over previous
//
#include <hip/hip_runtime.h>
#include <math.h>

// Problem dims (fixed)
constexpr int H_ = 1024;
constexpr int I_ = 2816;
constexpr int E_ = 8;
constexpr int T_ = 1024;   // S*B tokens

typedef __bf16 bf16x8 __attribute__((ext_vector_type(8)));
typedef float f32x4 __attribute__((ext_vector_type(4)));

__device__ __forceinline__ ushort f2bf(float f) {
    uint32_t u = __float_as_uint(f);
    u += 0x7fff + ((u >> 16) & 1);   // round-to-nearest-even
    return (ushort)(u >> 16);
}
__device__ __forceinline__ uint pack2(float lo, float hi) {
    return (uint)f2bf(lo) | ((uint)f2bf(hi) << 16);
}

// ws layout: int counts[8]; int tlist[8*1024]; ushort xbf[1024*1024]; ushort act[1024*2816]

__global__ __launch_bounds__(64) void router_kernel(const float* __restrict__ hidden,
                                                    const float* __restrict__ rw,
                                                    int* __restrict__ counts,
                                                    int* __restrict__ tlist,
                                                    ushort* __restrict__ xbf) {
    const int t = blockIdx.x;
    const int lane = threadIdx.x;
    const float* x = hidden + (size_t)t * H_ + lane * 16;
    float4 v[4];
#pragma unroll
    for (int j = 0; j < 4; j++) v[j] = ((const float4*)x)[j];
    uint2* xb = (uint2*)(xbf + (size_t)t * H_ + lane * 16);
#pragma unroll
    for (int j = 0; j < 4; j++) xb[j] = make_uint2(pack2(v[j].x, v[j].y), pack2(v[j].z, v[j].w));
    float acc[E_];
#pragma unroll
    for (int e = 0; e < E_; e++) {
        const float4* r = (const float4*)(rw + e * H_ + lane * 16);
        float a = 0.f;
#pragma unroll
        for (int j = 0; j < 4; j++) {
            float4 rv = r[j];
            a += v[j].x * rv.x + v[j].y * rv.y + v[j].z * rv.z + v[j].w * rv.w;
        }
        acc[e] = a;
    }
#pragma unroll
    for (int e = 0; e < E_; e++) {
#pragma unroll
        for (int off = 32; off >= 1; off >>= 1)
            acc[e] += __shfl_xor(acc[e], off, 64);
    }
    if (lane == 0) {
        int best = 0;
        float bv = acc[0];
#pragma unroll
        for (int e = 1; e < E_; e++) {
            if (acc[e] > bv) { bv = acc[e]; best = e; }  // strict > : first max wins
        }
        int pos = atomicAdd(&counts[best], 1);
        tlist[best * T_ + pos] = t;
    }
}

// Phase A: per expert e, N-tile of 32 I-rows, M=256 tokens, BK=64, bf16 MFMA.
__global__ __launch_bounds__(256, 3) void gateup_kernel(const ushort* __restrict__ xbf,
                                                        const float* __restrict__ gate_w,
                                                        const float* __restrict__ up_w,
                                                        const int* __restrict__ counts,
                                                        const int* __restrict__ tlist,
                                                        ushort* __restrict__ act) {
    const int e  = blockIdx.y;
    const int i0 = blockIdx.x * 32;
    const int cnt = counts[e];
    const int tid = threadIdx.x;

    __shared__ ushort Xs[256 * 72];
    __shared__ ushort Gs[32 * 72];
    __shared__ ushort Us[32 * 72];
    __shared__ int toks[256];

    const int wv = tid >> 6, lane = tid & 63, quad = lane >> 4, l15 = lane & 15;
    const float* gw = gate_w + (size_t)e * I_ * H_ + (size_t)i0 * H_;
    const float* uw = up_w   + (size_t)e * I_ * H_ + (size_t)i0 * H_;

    for (int toff = 0; toff < cnt; toff += 256) {
        __syncthreads();
        {
            int p = toff + tid;
            toks[tid] = (p < cnt) ? tlist[e * T_ + p] : -1;
        }
        __syncthreads();
        int tokr[8];
#pragma unroll
        for (int p = 0; p < 8; p++) tokr[p] = toks[(tid + p * 256) >> 3];

        f32x4 accg[4][2], accu[4][2];
#pragma unroll
        for (int mi = 0; mi < 4; mi++)
#pragma unroll
            for (int nj = 0; nj < 2; nj++) {
                accg[mi][nj] = (f32x4){0.f, 0.f, 0.f, 0.f};
                accu[mi][nj] = (f32x4){0.f, 0.f, 0.f, 0.f};
            }

        uint4 xv[8];
        float4 gv[2], uv[2];
        // preload k0 = 0
#pragma unroll
        for (int p = 0; p < 8; p++) {
            int idx = tid + p * 256;
            xv[p] = (tokr[p] >= 0)
                ? *(const uint4*)(xbf + (size_t)tokr[p] * H_ + ((idx & 7) << 3))
                : make_uint4(0u, 0u, 0u, 0u);
        }
#pragma unroll
        for (int p = 0; p < 2; p++) {
            int idx = tid + p * 256;
            int row = idx >> 4, c4 = (idx & 15) << 2;
            gv[p] = *(const float4*)(gw + (size_t)row * H_ + c4);
            uv[p] = *(const float4*)(uw + (size_t)row * H_ + c4);
        }

        for (int k0 = 0; k0 < H_; k0 += 64) {
            __syncthreads();   // prior MFMA phase done with LDS
#pragma unroll
            for (int p = 0; p < 8; p++) {
                int idx = tid + p * 256;
                *(uint4*)&Xs[(idx >> 3) * 72 + ((idx & 7) << 3)] = xv[p];
            }
#pragma unroll
            for (int p = 0; p < 2; p++) {
                int idx = tid + p * 256;
                int row = idx >> 4, c4 = (idx & 15) << 2;
                *(uint2*)&Gs[row * 72 + c4] = make_uint2(pack2(gv[p].x, gv[p].y), pack2(gv[p].z, gv[p].w));
                *(uint2*)&Us[row * 72 + c4] = make_uint2(pack2(uv[p].x, uv[p].y), pack2(uv[p].z, uv[p].w));
            }
            if (k0 + 64 < H_) {   // prefetch next iter: hides under MFMA phase
                int kn = k0 + 64;
#pragma unroll
                for (int p = 0; p < 8; p++) {
                    int idx = tid + p * 256;
                    xv[p] = (tokr[p] >= 0)
                        ? *(const uint4*)(xbf + (size_t)tokr[p] * H_ + kn + ((idx & 7) << 3))
                        : make_uint4(0u, 0u, 0u, 0u);
                }
#pragma unroll
                for (int p = 0; p < 2; p++) {
                    int idx = tid + p * 256;
                    int row = idx >> 4, c4 = (idx & 15) << 2;
                    gv[p] = *(const float4*)(gw + (size_t)row * H_ + kn + c4);
                    uv[p] = *(const float4*)(uw + (size_t)row * H_ + kn + c4);
                }
            }
            __syncthreads();
#pragma unroll
            for (int kk = 0; kk < 64; kk += 32) {
                const int kb = kk + quad * 8;
                bf16x8 bg[2], bu[2], a[4];
#pragma unroll
                for (int nj = 0; nj < 2; nj++) {
                    bg[nj] = *(const bf16x8*)&Gs[(nj * 16 + l15) * 72 + kb];
                    bu[nj] = *(const bf16x8*)&Us[(nj * 16 + l15) * 72 + kb];
                }
#pragma unroll
                for (int mi = 0; mi < 4; mi++)
                    a[mi] = *(const bf16x8*)&Xs[(wv * 64 + mi * 16 + l15) * 72 + kb];
#pragma unroll
                for (int mi = 0; mi < 4; mi++)
#pragma unroll
                    for (int nj = 0; nj < 2; nj++) {
                        accg[mi][nj] = __builtin_amdgcn_mfma_f32_16x16x32_bf16(a[mi], bg[nj], accg[mi][nj], 0, 0, 0);
                        accu[mi][nj] = __builtin_amdgcn_mfma_f32_16x16x32_bf16(a[mi], bu[nj], accu[mi][nj], 0, 0, 0);
                    }
            }
        }

#pragma unroll
        for (int mi = 0; mi < 4; mi++)
#pragma unroll
            for (int r = 0; r < 4; r++) {
                int tok = toks[wv * 64 + mi * 16 + quad * 4 + r];
                if (tok < 0) continue;
#pragma unroll
                for (int nj = 0; nj < 2; nj++) {
                    float g = accg[mi][nj][r], u = accu[mi][nj][r];
                    float s = g / (1.f + __expf(-g)) * u;
                    act[(size_t)tok * I_ + i0 + nj * 16 + l15] = f2bf(s);
                }
            }
    }
}

// Phase B: per expert e, N-tile of 32 H-rows, M=256 tokens, K=I=2816, BK=64.
__global__ __launch_bounds__(256, 3) void down_kernel(const ushort* __restrict__ act,
                                                      const float* __restrict__ down_w,
                                                      const int* __restrict__ counts,
                                                      const int* __restrict__ tlist,
                                                      float* __restrict__ out) {
    const int e  = blockIdx.y;
    const int h0 = blockIdx.x * 32;
    const int cnt = counts[e];
    const int tid = threadIdx.x;

    __shared__ ushort As[256 * 72];
    __shared__ ushort Ds[32 * 72];
    __shared__ int toks[256];

    const int wv = tid >> 6, lane = tid & 63, quad = lane >> 4, l15 = lane & 15;
    const float* dw = down_w + (size_t)e * H_ * I_ + (size_t)h0 * I_;

    for (int toff = 0; toff < cnt; toff += 256) {
        __syncthreads();
        {
            int p = toff + tid;
            toks[tid] = (p < cnt) ? tlist[e * T_ + p] : -1;
        }
        __syncthreads();
        int tokr[8];
#pragma unroll
        for (int p = 0; p < 8; p++) tokr[p] = toks[(tid + p * 256) >> 3];

        f32x4 acc[4][2];
#pragma unroll
        for (int mi = 0; mi < 4; mi++)
#pragma unroll
            for (int nj = 0; nj < 2; nj++) acc[mi][nj] = (f32x4){0.f, 0.f, 0.f, 0.f};

        uint4 av[8];
        float4 dv[2];
#pragma unroll
        for (int p = 0; p < 8; p++) {
            int idx = tid + p * 256;
            av[p] = (tokr[p] >= 0)
                ? *(const uint4*)(act + (size_t)tokr[p] * I_ + ((idx & 7) << 3))
                : make_uint4(0u, 0u, 0u, 0u);
        }
#pragma unroll
        for (int p = 0; p < 2; p++) {
            int idx = tid + p * 256;
            int row = idx >> 4, c4 = (idx & 15) << 2;
            dv[p] = *(const float4*)(dw + (size_t)row * I_ + c4);
        }

        for (int k0 = 0; k0 < I_; k0 += 64) {
            __syncthreads();
#pragma unroll
            for (int p = 0; p < 8; p++) {
                int idx = tid + p * 256;
                *(uint4*)&As[(idx >> 3) * 72 + ((idx & 7) << 3)] = av[p];
            }
#pragma unroll
            for (int p = 0; p < 2; p++) {
                int idx = tid + p * 256;
                int row = idx >> 4, c4 = (idx & 15) << 2;
                *(uint2*)&Ds[row * 72 + c4] = make_uint2(pack2(dv[p].x, dv[p].y), pack2(dv[p].z, dv[p].w));
            }
            if (k0 + 64 < I_) {
                int kn = k0 + 64;
#pragma unroll
                for (int p = 0; p < 8; p++) {
                    int idx = tid + p * 256;
                    av[p] = (tokr[p] >= 0)
                        ? *(const uint4*)(act + (size_t)tokr[p] * I_ + kn + ((idx & 7) << 3))
                        : make_uint4(0u, 0u, 0u, 0u);
                }
#pragma unroll
                for (int p = 0; p < 2; p++) {
                    int idx = tid + p * 256;
                    int row = idx >> 4, c4 = (idx & 15) << 2;
                    dv[p] = *(const float4*)(dw + (size_t)row * I_ + kn + c4);
                }
            }
            __syncthreads();
#pragma unroll
            for (int kk = 0; kk < 64; kk += 32) {
                const int kb = kk + quad * 8;
                bf16x8 b[2], a[4];
#pragma unroll
                for (int nj = 0; nj < 2; nj++)
                    b[nj] = *(const bf16x8*)&Ds[(nj * 16 + l15) * 72 + kb];
#pragma unroll
                for (int mi = 0; mi < 4; mi++)
                    a[mi] = *(const bf16x8*)&As[(wv * 64 + mi * 16 + l15) * 72 + kb];
#pragma unroll
                for (int mi = 0; mi < 4; mi++)
#pragma unroll
                    for (int nj = 0; nj < 2; nj++)
                        acc[mi][nj] = __builtin_amdgcn_mfma_f32_16x16x32_bf16(a[mi], b[nj], acc[mi][nj], 0, 0, 0);
            }
        }

#pragma unroll
        for (int mi = 0; mi < 4; mi++)
#pragma unroll
            for (int r = 0; r < 4; r++) {
                int tok = toks[wv * 64 + mi * 16 + quad * 4 + r];
                if (tok < 0) continue;
#pragma unroll
                for (int nj = 0; nj < 2; nj++)
                    out[(size_t)tok * H_ + h0 + nj * 16 + l15] = acc[mi][nj][r];
            }
    }
}

extern "C" void kernel_launch(void* const* d_in, const int* in_sizes, int n_in,
                              void* d_out, int out_size, void* d_ws, size_t ws_size,
                              hipStream_t stream) {
    const float* hidden = (const float*)d_in[0];
    const float* rw     = (const float*)d_in[1];
    const float* gate_w = (const float*)d_in[2];
    const float* up_w   = (const float*)d_in[3];
    const float* down_w = (const float*)d_in[4];
    float* out = (float*)d_out;

    int* counts = (int*)d_ws;
    int* tlist  = counts + E_;
    ushort* xbf = (ushort*)(tlist + E_ * T_);          // 2 MB
    ushort* act = xbf + (size_t)T_ * H_;               // 5.77 MB

    hipMemsetAsync(counts, 0, E_ * sizeof(int), stream);
    hipLaunchKernelGGL(router_kernel, dim3(T_), dim3(64), 0, stream, hidden, rw, counts, tlist, xbf);
    hipLaunchKernelGGL(gateup_kernel, dim3(I_ / 32, E_), dim3(256), 0, stream,
                       xbf, gate_w, up_w, counts, tlist, act);
    hipLaunchKernelGGL(down_kernel, dim3(H_ / 32, E_), dim3(256), 0, stream,
                       act, down_w, counts, tlist, out);
}